// Round 3
// baseline (149.471 us; speedup 1.0000x reference)
//
#include <hip/hip_runtime.h>
#include <hip/hip_bf16.h>

#define FLOAT_EPS 1.1920928955078125e-07f

typedef float f32x4 __attribute__((ext_vector_type(4)));
typedef short s16x8 __attribute__((ext_vector_type(8)));

#define B_ 16
#define P_ 8192
#define I_ 256
#define O_ 128
#define L_ 256
#define IO_ (I_*O_)   // 32768

__device__ __forceinline__ float clip01(float v) {
    return fminf(fmaxf(v, 0.0f), 1.0f);
}

// ---------------- K1: partial logits, l split 2-way; lat read via scalar loads ------
// grid (128, 2, 2) = (n-block, ks, l-half), block 256.
// lgP[(lh*32 + ks*16 + b)*IO + n] = sum_{l in half} lat[b][lh*128+l]*C[l][n]
__global__ __launch_bounds__(256) void rl_k1_logits(
        const float* __restrict__ lat,
        const float* __restrict__ c1, const float* __restrict__ c2,
        float* __restrict__ lgP) {
    const int n  = blockIdx.x * 256 + threadIdx.x;
    const int ks = blockIdx.y;
    const int lh = blockIdx.z;
    const float* __restrict__ C  = (ks ? c2 : c1) + (size_t)lh * 128 * IO_;
    const int lbase = lh * 128;

    float acc[16];
#pragma unroll
    for (int b = 0; b < 16; ++b) acc[b] = 0.0f;

#pragma unroll 4
    for (int l = 0; l < 128; ++l) {
        float cv = C[(size_t)l * IO_ + n];
#pragma unroll
        for (int b = 0; b < 16; ++b)
            acc[b] += lat[b * L_ + lbase + l] * cv;   // uniform -> s_load
    }
    float* o = lgP + ((size_t)(lh * 32 + ks * 16)) * IO_ + n;
#pragma unroll
    for (int b = 0; b < 16; ++b) o[(size_t)b * IO_] = acc[b];
}

// ---------------- K2: double softmax over i, write M_T[b][n][i] bf16 ----------------
// grid (8, 2, 16) = (o-tile16, ks, b), block 256 = 16 i-groups x 16 o-lanes.
__global__ __launch_bounds__(256) void rl_k2_mask(
        const float* __restrict__ lgP, const float* __restrict__ u,
        const float* __restrict__ temp_p, __hip_bfloat16* __restrict__ MT) {
    const int oo = threadIdx.x & 15;
    const int g  = threadIdx.x >> 4;     // 16 groups, 16 i's each
    const int o0 = blockIdx.x * 16;
    const int ks = blockIdx.y;
    const int b  = blockIdx.z;

    __shared__ float slab[I_][16];
    __shared__ float red[16][16];

    const float* __restrict__ z0 = lgP + (size_t)(ks * 16 + b) * IO_ + o0 + oo;
    const float* __restrict__ z1 = z0 + (size_t)32 * IO_;
    const float* __restrict__ up = u + ((size_t)b * 2 + ks) * IO_ + o0 + oo;

    float T = temp_p[0];
    T = fminf(fmaxf(T, FLOAT_EPS), 2.0f);
    T = fmaxf(T, 0.001f);
    const float rT = 1.0f / T;

    const int i0 = g * 16, i1 = i0 + 16;

    // pass 0: combine partial logits into LDS column
    for (int i = i0; i < i1; ++i)
        slab[i][oo] = z0[(size_t)i * O_] + z1[(size_t)i * O_];
    __syncthreads();

    // pass 1: max over i
    float m = -INFINITY;
    for (int i = i0; i < i1; ++i) m = fmaxf(m, slab[i][oo]);
    red[g][oo] = m; __syncthreads();
    m = -INFINITY;
#pragma unroll
    for (int j = 0; j < 16; ++j) m = fmaxf(m, red[j][oo]);
    __syncthreads();

    // pass 2: sum exp
    float S = 0.0f;
    for (int i = i0; i < i1; ++i) S += expf(slab[i][oo] - m);
    red[g][oo] = S; __syncthreads();
    S = 0.0f;
#pragma unroll
    for (int j = 0; j < 16; ++j) S += red[j][oo];
    __syncthreads();
    const float invS = 1.0f / S;

    // pass 3: s_i = (log(p_i + eps) + g_i)/T ; overwrite slab; track max
    float m2 = -INFINITY;
    for (int i = i0; i < i1; ++i) {
        float p  = expf(slab[i][oo] - m) * invS;
        float uu = fmaxf(up[(size_t)i * O_], FLOAT_EPS);
        float gg = -logf(-logf(uu));
        float s  = (logf(p + FLOAT_EPS) + gg) * rT;
        slab[i][oo] = s;
        m2 = fmaxf(m2, s);
    }
    red[g][oo] = m2; __syncthreads();
    m2 = -INFINITY;
#pragma unroll
    for (int j = 0; j < 16; ++j) m2 = fmaxf(m2, red[j][oo]);
    __syncthreads();

    // pass 4: sum exp of s
    float S2 = 0.0f;
    for (int i = i0; i < i1; ++i) S2 += expf(slab[i][oo] - m2);
    red[g][oo] = S2; __syncthreads();
    S2 = 0.0f;
#pragma unroll
    for (int j = 0; j < 16; ++j) S2 += red[j][oo];
    const float invS2 = 1.0f / S2;

    // pass 5: write mask_s bf16 into M_T[b][n = ks*128 + o][i]
    __hip_bfloat16* __restrict__ row = MT + ((size_t)(b * 256 + ks * 128 + o0 + oo)) * I_;
    for (int i = i0; i < i1; i += 2) {
        float v0 = expf(slab[i][oo]     - m2) * invS2;
        float v1 = expf(slab[i + 1][oo] - m2) * invS2;
        __hip_bfloat162 pk = __float22bfloat162_rn(make_float2(v0, v1));
        *(__hip_bfloat162*)(row + i) = pk;
    }
}

// ---------------- K3: software-pipelined streaming GEMM, B resident in LDS ----------
// grid (16, 16) = (512-row slab, b), block 512 = 8 waves, 64 rows/wave in 4 chunks of 16.
// Pipeline: cvt(c) -> prefetch raw(c+1) -> MFMA(c) -> store(c). No barriers in loop.
__global__ __launch_bounds__(512, 2) void rl_k3_gemm(
        const float* __restrict__ X, const __hip_bfloat16* __restrict__ MT,
        float* __restrict__ OUT) {
    const int tid  = threadIdx.x;
    const int lane = tid & 63, wid = tid >> 6;
    const int b    = blockIdx.y;

    __shared__ short Blds[256 * 256];   // 128 KB, XOR-swizzled byte ^= (n&7)<<4

    const float* __restrict__ Xb           = X   + (size_t)b * P_ * I_;
    const __hip_bfloat16* __restrict__ MTb = MT  + (size_t)b * 65536;
    float* __restrict__ Ob                 = OUT + (size_t)b * P_ * 512;

    // load B once (cooperative, swizzled)
#pragma unroll
    for (int it = 0; it < 16; ++it) {
        int idx = it * 512 + tid;          // chunks of 8 bf16
        int n = idx >> 5, c = idx & 31;
        s16x8 v = *(const s16x8*)(MTb + n * 256 + c * 8);
        *(s16x8*)((char*)Blds + n * 512 + ((c * 16) ^ ((n & 7) << 4))) = v;
    }
    __syncthreads();

    const int l15 = lane & 15, lhi = lane >> 4;
    const int rowbase = blockIdx.x * 512 + wid * 64 + l15;   // A-load row for chunk 0
    const int rb = lhi * 4;

    float4 raw[16];
    // prefetch chunk 0: 16 rows x 256 k, each lane 8 floats per 32-k window
    {
        const float* s0 = Xb + (size_t)rowbase * I_ + lhi * 8;
#pragma unroll
        for (int kk = 0; kk < 8; ++kk) {
            raw[2 * kk]     = *(const float4*)(s0 + kk * 32);
            raw[2 * kk + 1] = *(const float4*)(s0 + kk * 32 + 4);
        }
    }

    for (int c = 0; c < 4; ++c) {
        // convert raw -> af (consumes raw, frees it for next prefetch)
        s16x8 af[8];
#pragma unroll
        for (int kk = 0; kk < 8; ++kk) {
            float4 f0 = raw[2 * kk], f1 = raw[2 * kk + 1];
            union { s16x8 v; __hip_bfloat162 h[4]; } cv;
            cv.h[0] = __float22bfloat162_rn(make_float2(f0.x, f0.y));
            cv.h[1] = __float22bfloat162_rn(make_float2(f0.z, f0.w));
            cv.h[2] = __float22bfloat162_rn(make_float2(f1.x, f1.y));
            cv.h[3] = __float22bfloat162_rn(make_float2(f1.z, f1.w));
            af[kk] = cv.v;
        }
        // prefetch chunk c+1 BEFORE compute+store so loads stay in flight under them
        if (c < 3) {
            const float* s1 = Xb + (size_t)(rowbase + (c + 1) * 16) * I_ + lhi * 8;
#pragma unroll
            for (int kk = 0; kk < 8; ++kk) {
                raw[2 * kk]     = *(const float4*)(s1 + kk * 32);
                raw[2 * kk + 1] = *(const float4*)(s1 + kk * 32 + 4);
            }
        }

        f32x4 acc[16];
#pragma unroll
        for (int j = 0; j < 16; ++j) acc[j] = (f32x4){0.f, 0.f, 0.f, 0.f};

#pragma unroll
        for (int kk = 0; kk < 8; ++kk) {
            const int kb = kk * 64 + lhi * 16;   // byte offset in B row
#pragma unroll
            for (int fn = 0; fn < 16; ++fn) {
                int n = fn * 16 + l15;
                s16x8 bf = *(const s16x8*)((const char*)Blds + n * 512 + (kb ^ ((n & 7) << 4)));
                acc[fn] = __builtin_amdgcn_mfma_f32_16x16x32_bf16(af[kk], bf, acc[fn], 0, 0, 0);
            }
        }

        // epilogue: a = cols [0,128), b = cols [128,256)
        const int prow = blockIdx.x * 512 + wid * 64 + c * 16 + rb;
#pragma unroll
        for (int fn = 0; fn < 8; ++fn)
#pragma unroll
        for (int r = 0; r < 4; ++r) {
            float a  = acc[fn][r];
            float bb = acc[fn + 8][r];
            float* op = Ob + (size_t)(prow + r) * 512 + fn * 16 + l15;
            op[0]   = clip01(a + bb);
            op[128] = clip01(a + bb - 1.0f);
            op[256] = clip01(a - bb);
            op[384] = clip01(bb - a);
        }
    }
}

extern "C" void kernel_launch(void* const* d_in, const int* in_sizes, int n_in,
                              void* d_out, int out_size, void* d_ws, size_t ws_size,
                              hipStream_t stream) {
    const float* x    = (const float*)d_in[0];
    const float* lat  = (const float*)d_in[1];
    const float* c1   = (const float*)d_in[2];
    const float* c2   = (const float*)d_in[3];
    const float* temp = (const float*)d_in[4];
    const float* u    = (const float*)d_in[5];
    float* out = (float*)d_out;

    char* ws = (char*)d_ws;
    float*          lgP = (float*)ws;                          // 64 slabs * 128KB = 8 MB
    __hip_bfloat16* MT  = (__hip_bfloat16*)(ws + (8 << 20));   // 2 MB

    rl_k1_logits<<<dim3(128, 2, 2), 256, 0, stream>>>(lat, c1, c2, lgP);
    rl_k2_mask  <<<dim3(8, 2, 16), 256, 0, stream>>>(lgP, u, temp, MT);
    rl_k3_gemm  <<<dim3(16, 16), 512, 0, stream>>>(x, MT, out);
}